// Round 3
// baseline (28711.945 us; speedup 1.0000x reference)
//
#include <hip/hip_runtime.h>
#include <math.h>

// Round 3: persistent kernel with hand-rolled device-scope grid barrier
// (agent-scope atomics + __threadfence, per CDNA Guideline 16), launched via
// hipLaunchCooperativeKernel for the co-residency guarantee. Launch errors are
// CHECKED; on failure fall back to the verified round-1 multi-kernel schedule.

#define BB 8
#define TT 64
#define NN 256
#define HH 256
#define BN 2048
#define LSTR 72   // LDS row stride in ushorts for a 64-wide K chunk
#define GRID 512

typedef float f32x4 __attribute__((ext_vector_type(4)));
typedef short s16x8 __attribute__((ext_vector_type(8)));

#define MFMA(a, b, c) __builtin_amdgcn_mfma_f32_16x16x32_bf16(a, b, c, 0, 0, 0)

__device__ __forceinline__ ushort rne_bf16(float x) {
    unsigned u = __builtin_bit_cast(unsigned, x);
    unsigned r = u + 0x7FFFu + ((u >> 16) & 1u);
    return (ushort)(r >> 16);
}
__device__ __forceinline__ float bf16_f32(ushort h) {
    unsigned u = ((unsigned)h) << 16;
    return __builtin_bit_cast(float, u);
}
__device__ __forceinline__ void split2(float x, ushort& hi, ushort& lo) {
    ushort h = rne_bf16(x);
    hi = h;
    lo = rne_bf16(x - bf16_f32(h));
}

// ---------------------------------------------------------------------------
// grid barrier: sense-reversing, device(agent)-scope atomics + threadfence
// ---------------------------------------------------------------------------
struct BarMem { unsigned count; unsigned pad1[15]; unsigned gen; unsigned pad2[15]; };

__device__ __forceinline__ void grid_sync(BarMem* bar, unsigned nb) {
    __syncthreads();
    if (threadIdx.x == 0) {
        __threadfence();   // release: make this block's writes agent-visible
        unsigned old = __hip_atomic_load(&bar->gen, __ATOMIC_RELAXED,
                                         __HIP_MEMORY_SCOPE_AGENT);
        unsigned prev = __hip_atomic_fetch_add(&bar->count, 1u, __ATOMIC_ACQ_REL,
                                               __HIP_MEMORY_SCOPE_AGENT);
        if (prev == nb - 1u) {
            __hip_atomic_store(&bar->count, 0u, __ATOMIC_RELAXED,
                               __HIP_MEMORY_SCOPE_AGENT);
            __hip_atomic_fetch_add(&bar->gen, 1u, __ATOMIC_RELEASE,
                                   __HIP_MEMORY_SCOPE_AGENT);
        } else {
            while (__hip_atomic_load(&bar->gen, __ATOMIC_ACQUIRE,
                                     __HIP_MEMORY_SCOPE_AGENT) == old)
                __builtin_amdgcn_s_sleep(8);
        }
        __threadfence();   // acquire side: invalidate stale cached lines
    }
    __syncthreads();
}

// ---------------------------------------------------------------------------
// prep: round A to bf16; build transposed bf16 weight slabs [Ncols][256]
// ---------------------------------------------------------------------------
__global__ __launch_bounds__(256) void prep_kernel(const float* __restrict__ A,
    const float* __restrict__ Wh0, const float* __restrict__ Wx1,
    const float* __restrict__ Wh1,
    ushort* Abf, ushort* WzrT0, ushort* WcT0, ushort* WxzrT1,
    ushort* WhzrT1, ushort* WxcT1, ushort* WhcT1)
{
    int idx = blockIdx.x * 256 + threadIdx.x;
    if (idx < 65536) { Abf[idx] = rne_bf16(A[idx]); return; }
    int e = idx - 65536;
    ushort* dst; const float* src; int colOff;
    if      (e < 131072) { dst = WzrT0;  src = Wh0; colOff = 0;   }
    else if (e < 196608) { dst = WcT0;   src = Wh0; colOff = 512; e -= 131072; }
    else if (e < 327680) { dst = WxzrT1; src = Wx1; colOff = 0;   e -= 196608; }
    else if (e < 458752) { dst = WhzrT1; src = Wh1; colOff = 0;   e -= 327680; }
    else if (e < 524288) { dst = WxcT1;  src = Wx1; colOff = 512; e -= 458752; }
    else if (e < 589824) { dst = WhcT1;  src = Wh1; colOff = 512; e -= 524288; }
    else return;
    int c = e >> 8, k = e & 255;
    dst[e] = rne_bf16(src[k * 768 + colOff + c]);
}

// ---------------------------------------------------------------------------
// device job bodies (identical numerics to round 1)
// ---------------------------------------------------------------------------
__device__ void x_job(int lb, int tid, float* xs, float* red, const float* Af,
                      const float* x2d, const float* mask, float* Ax0, int t) {
    int b = lb >> 2, rt = lb & 3;
    const float* xbase = x2d + ((size_t)(b * TT + t) * NN) * 6;
    const float* mbase = mask + (size_t)(b * TT + t) * NN;
    {
        int m = tid;
        float mk = mbase[m];
        #pragma unroll
        for (int d = 0; d < 6; ++d) xs[m * 8 + d] = xbase[m * 6 + d] * mk;
    }
    __syncthreads();
    int i = tid & 63, q = tid >> 6;
    const float* arow = Af + (size_t)(rt * 64 + i) * 256 + q * 64;
    float a6[6] = {0.f, 0.f, 0.f, 0.f, 0.f, 0.f};
    for (int m = 0; m < 64; ++m) {
        float a = arow[m];
        const float* xv = &xs[(q * 64 + m) * 8];
        #pragma unroll
        for (int d = 0; d < 6; ++d) a6[d] = fmaf(a, xv[d], a6[d]);
    }
    #pragma unroll
    for (int d = 0; d < 6; ++d) red[(i * 4 + q) * 8 + d] = a6[d];
    __syncthreads();
    for (int idx2 = tid; idx2 < 64 * 6; idx2 += 256) {
        int ii = idx2 / 6, d = idx2 - ii * 6;
        float s = red[(ii * 4 + 0) * 8 + d] + red[(ii * 4 + 1) * 8 + d]
                + red[(ii * 4 + 2) * 8 + d] + red[(ii * 4 + 3) * 8 + d];
        Ax0[(size_t)(b * 256 + rt * 64 + ii) * 8 + d] = s;
    }
    __syncthreads();
}

__device__ void head_job(int lb, int tid, const float* h1, const float* Wout,
                         const float* bout, float* out, int tprev) {
    int g = lb * 256 + tid;
    int row = g / 9, o = g - row * 9;
    if (row >= BN) return;
    const float* hr = h1 + (size_t)row * 256;
    float s = bout[o];
    for (int k = 0; k < 256; k += 4) {
        float4 hv = *(const float4*)(hr + k);
        s = fmaf(hv.x, Wout[(k + 0) * 9 + o], s);
        s = fmaf(hv.y, Wout[(k + 1) * 9 + o], s);
        s = fmaf(hv.z, Wout[(k + 2) * 9 + o], s);
        s = fmaf(hv.w, Wout[(k + 3) * 9 + o], s);
    }
    int b = row >> 8, n = row & 255;
    out[((size_t)(b * TT + tprev) * NN + n) * 9 + o] = s;
}

// g2 job: one 64x64 tile of Y(hi/lo) = A_bf16 @ XT(hi+lo), lb in [0,128)
__device__ void g2_job(int lb, int tid, ushort* lds, const ushort* Abf,
                       const ushort* XThi, const ushort* XTlo,
                       ushort* Yhi, ushort* Ylo) {
    ushort* As   = lds;
    ushort* Bshi = lds + 64 * LSTR;
    ushort* Bslo = lds + 2 * 64 * LSTR;
    const int b = lb >> 4, rt = (lb >> 2) & 3, ct = lb & 3;

    const int lane = tid & 63, wave = tid >> 6;
    const int wr = wave >> 1, wc = wave & 1;
    const int l15 = lane & 15, q8 = (lane >> 4) << 3;

    f32x4 acc[2][2];
    acc[0][0] = 0.f; acc[0][1] = 0.f; acc[1][0] = 0.f; acc[1][1] = 0.f;

    const int rr = tid >> 2, ko = (tid & 3) << 4;
    const ushort* Asrc = Abf + (size_t)(rt * 64 + rr) * 256 + ko;
    const ushort* Bh   = XThi + (size_t)(b * 256 + ct * 64 + rr) * 256 + ko;
    const ushort* Bl   = XTlo + (size_t)(b * 256 + ct * 64 + rr) * 256 + ko;
    ushort* wA = &As[rr * LSTR + ko];
    ushort* wH = &Bshi[rr * LSTR + ko];
    ushort* wL = &Bslo[rr * LSTR + ko];

    for (int k0 = 0; k0 < 256; k0 += 64) {
        __syncthreads();
        *(uint4*)(wA)     = *(const uint4*)(Asrc + k0);
        *(uint4*)(wA + 8) = *(const uint4*)(Asrc + k0 + 8);
        *(uint4*)(wH)     = *(const uint4*)(Bh + k0);
        *(uint4*)(wH + 8) = *(const uint4*)(Bh + k0 + 8);
        *(uint4*)(wL)     = *(const uint4*)(Bl + k0);
        *(uint4*)(wL + 8) = *(const uint4*)(Bl + k0 + 8);
        __syncthreads();
        #pragma unroll
        for (int sub = 0; sub < 2; ++sub) {
            const int kb = sub * 32 + q8;
            s16x8 a0  = *(const s16x8*)&As[(wr * 32 + l15) * LSTR + kb];
            s16x8 a1  = *(const s16x8*)&As[(wr * 32 + 16 + l15) * LSTR + kb];
            s16x8 bh0 = *(const s16x8*)&Bshi[(wc * 32 + l15) * LSTR + kb];
            s16x8 bh1 = *(const s16x8*)&Bshi[(wc * 32 + 16 + l15) * LSTR + kb];
            s16x8 bl0 = *(const s16x8*)&Bslo[(wc * 32 + l15) * LSTR + kb];
            s16x8 bl1 = *(const s16x8*)&Bslo[(wc * 32 + 16 + l15) * LSTR + kb];
            acc[0][0] = MFMA(a0, bh0, acc[0][0]);
            acc[0][0] = MFMA(a0, bl0, acc[0][0]);
            acc[0][1] = MFMA(a0, bh1, acc[0][1]);
            acc[0][1] = MFMA(a0, bl1, acc[0][1]);
            acc[1][0] = MFMA(a1, bh0, acc[1][0]);
            acc[1][0] = MFMA(a1, bl0, acc[1][0]);
            acc[1][1] = MFMA(a1, bh1, acc[1][1]);
            acc[1][1] = MFMA(a1, bl1, acc[1][1]);
        }
    }
    const int quad = lane >> 4;
    #pragma unroll
    for (int i = 0; i < 2; ++i) {
        #pragma unroll
        for (int j = 0; j < 2; ++j) {
            const int col = ct * 64 + wc * 32 + j * 16 + l15;
            const int m0  = rt * 64 + wr * 32 + i * 16 + quad * 4;
            const size_t base = (size_t)(b * 256 + m0) * 256 + col;
            #pragma unroll
            for (int r = 0; r < 4; ++r) {
                ushort hi, lo;
                split2(acc[i][j][r], hi, lo);
                Yhi[base + (size_t)r * 256] = hi;
                Ylo[base + (size_t)r * 256] = lo;
            }
        }
    }
    __syncthreads();
}

// wact job: gate GEMM + epilogue
struct WSub {
    const ushort* Lhi0; const ushort* Llo0; const ushort* RT0;
    const ushort* Lhi1; const ushort* Llo1; const ushort* RT1;
    int ngemm;
    const float* bias;
    int useK6; int wxColOff;
    const float* h;
    float* z;
    float* hOut;
    ushort* Thi; ushort* Tlo;
};

__device__ void wact_job(int lb, int tid, ushort* lds, const WSub& u, int mode,
                         const float* Ax0, const float* Wx0) {
    ushort* Ashi = lds;
    ushort* Aslo = lds + 64 * LSTR;
    ushort* Bs   = lds + 2 * 64 * LSTR;
    int b, rt, ct;
    if (mode == 0) { b = lb >> 5; rt = (lb >> 3) & 3; ct = lb & 7; }
    else           { b = lb >> 4; rt = (lb >> 2) & 3; ct = lb & 3; }

    const int lane = tid & 63, wave = tid >> 6;
    const int wr = wave >> 1, wc = wave & 1;
    const int l15 = lane & 15, q8 = (lane >> 4) << 3;

    f32x4 acc[2][2];
    acc[0][0] = 0.f; acc[0][1] = 0.f; acc[1][0] = 0.f; acc[1][1] = 0.f;

    const int rr = tid >> 2, ko = (tid & 3) << 4;
    for (int g = 0; g < u.ngemm; ++g) {
        const ushort* Lh = (g ? u.Lhi1 : u.Lhi0) + (size_t)(b * 256 + rt * 64 + rr) * 256 + ko;
        const ushort* Ll = (g ? u.Llo1 : u.Llo0) + (size_t)(b * 256 + rt * 64 + rr) * 256 + ko;
        const ushort* Rt = (g ? u.RT1  : u.RT0 ) + (size_t)(ct * 64 + rr) * 256 + ko;
        ushort* wA = &Ashi[rr * LSTR + ko];
        ushort* wL = &Aslo[rr * LSTR + ko];
        ushort* wB = &Bs[rr * LSTR + ko];
        for (int k0 = 0; k0 < 256; k0 += 64) {
            __syncthreads();
            *(uint4*)(wA)     = *(const uint4*)(Lh + k0);
            *(uint4*)(wA + 8) = *(const uint4*)(Lh + k0 + 8);
            *(uint4*)(wL)     = *(const uint4*)(Ll + k0);
            *(uint4*)(wL + 8) = *(const uint4*)(Ll + k0 + 8);
            *(uint4*)(wB)     = *(const uint4*)(Rt + k0);
            *(uint4*)(wB + 8) = *(const uint4*)(Rt + k0 + 8);
            __syncthreads();
            #pragma unroll
            for (int sub = 0; sub < 2; ++sub) {
                const int kb = sub * 32 + q8;
                s16x8 ah0 = *(const s16x8*)&Ashi[(wr * 32 + l15) * LSTR + kb];
                s16x8 ah1 = *(const s16x8*)&Ashi[(wr * 32 + 16 + l15) * LSTR + kb];
                s16x8 al0 = *(const s16x8*)&Aslo[(wr * 32 + l15) * LSTR + kb];
                s16x8 al1 = *(const s16x8*)&Aslo[(wr * 32 + 16 + l15) * LSTR + kb];
                s16x8 b0  = *(const s16x8*)&Bs[(wc * 32 + l15) * LSTR + kb];
                s16x8 b1  = *(const s16x8*)&Bs[(wc * 32 + 16 + l15) * LSTR + kb];
                acc[0][0] = MFMA(ah0, b0, acc[0][0]);
                acc[0][0] = MFMA(al0, b0, acc[0][0]);
                acc[0][1] = MFMA(ah0, b1, acc[0][1]);
                acc[0][1] = MFMA(al0, b1, acc[0][1]);
                acc[1][0] = MFMA(ah1, b0, acc[1][0]);
                acc[1][0] = MFMA(al1, b0, acc[1][0]);
                acc[1][1] = MFMA(ah1, b1, acc[1][1]);
                acc[1][1] = MFMA(al1, b1, acc[1][1]);
            }
        }
    }

    const int quad = lane >> 4;
    const int m0base = rt * 64 + wr * 32;
    int colg[2];
    #pragma unroll
    for (int j = 0; j < 2; ++j) colg[j] = ct * 64 + wc * 32 + j * 16 + l15;
    float bv[2] = { u.bias[colg[0]], u.bias[colg[1]] };
    float v[2][2][4];
    #pragma unroll
    for (int i = 0; i < 2; ++i)
        #pragma unroll
        for (int j = 0; j < 2; ++j)
            #pragma unroll
            for (int r = 0; r < 4; ++r)
                v[i][j][r] = acc[i][j][r] + bv[j];

    if (u.useK6) {
        float w6[2][6];
        #pragma unroll
        for (int j = 0; j < 2; ++j)
            #pragma unroll
            for (int d = 0; d < 6; ++d)
                w6[j][d] = Wx0[d * 768 + u.wxColOff + colg[j]];
        #pragma unroll
        for (int i = 0; i < 2; ++i) {
            #pragma unroll
            for (int r = 0; r < 4; ++r) {
                int row = b * 256 + m0base + i * 16 + quad * 4 + r;
                const float* ax = Ax0 + (size_t)row * 8;
                float a0 = ax[0], a1 = ax[1], a2 = ax[2], a3 = ax[3], a4 = ax[4], a5 = ax[5];
                #pragma unroll
                for (int j = 0; j < 2; ++j)
                    v[i][j][r] += a0 * w6[j][0] + a1 * w6[j][1] + a2 * w6[j][2]
                                + a3 * w6[j][3] + a4 * w6[j][4] + a5 * w6[j][5];
            }
        }
    }

    if (mode == 0) {
        if (ct < 4) {
            #pragma unroll
            for (int i = 0; i < 2; ++i)
                #pragma unroll
                for (int r = 0; r < 4; ++r) {
                    int row = b * 256 + m0base + i * 16 + quad * 4 + r;
                    #pragma unroll
                    for (int j = 0; j < 2; ++j)
                        u.z[(size_t)row * 256 + colg[j]] = 1.f / (1.f + __expf(-v[i][j][r]));
                }
        } else {
            #pragma unroll
            for (int i = 0; i < 2; ++i) {
                int m0 = m0base + i * 16 + quad * 4;
                #pragma unroll
                for (int j = 0; j < 2; ++j) {
                    int colp = colg[j] - 256;
                    ushort hi4[4], lo4[4];
                    #pragma unroll
                    for (int r = 0; r < 4; ++r) {
                        int row = b * 256 + m0 + r;
                        float s = 1.f / (1.f + __expf(-v[i][j][r]));
                        float rh = s * u.h[(size_t)row * 256 + colp];
                        split2(rh, hi4[r], lo4[r]);
                    }
                    size_t off = (size_t)b * 65536 + (size_t)colp * 256 + m0;
                    *(ushort4*)&u.Thi[off] = make_ushort4(hi4[0], hi4[1], hi4[2], hi4[3]);
                    *(ushort4*)&u.Tlo[off] = make_ushort4(lo4[0], lo4[1], lo4[2], lo4[3]);
                }
            }
        }
    } else {
        #pragma unroll
        for (int i = 0; i < 2; ++i) {
            int m0 = m0base + i * 16 + quad * 4;
            #pragma unroll
            for (int j = 0; j < 2; ++j) {
                ushort hi4[4], lo4[4];
                #pragma unroll
                for (int r = 0; r < 4; ++r) {
                    int row = b * 256 + m0 + r;
                    size_t gi = (size_t)row * 256 + colg[j];
                    float c = tanhf(v[i][j][r]);
                    float zz = u.z[gi];
                    float hh = u.h[gi];
                    float hn = zz * hh + (1.f - zz) * c;
                    u.hOut[gi] = hn;
                    split2(hn, hi4[r], lo4[r]);
                }
                size_t off = (size_t)b * 65536 + (size_t)colg[j] * 256 + m0;
                *(ushort4*)&u.Thi[off] = make_ushort4(hi4[0], hi4[1], hi4[2], hi4[3]);
                *(ushort4*)&u.Tlo[off] = make_ushort4(lo4[0], lo4[1], lo4[2], lo4[3]);
            }
        }
    }
    __syncthreads();
}

// ---------------------------------------------------------------------------
// shared phase runner (used by both the persistent kernel and the fallback)
// ---------------------------------------------------------------------------
struct FP {
    const ushort* Abf;
    const float* Af; const float* x2d; const float* mask;
    const float* Wx0; const float* b0; const float* b1;
    const float* Wout; const float* bout; float* out;
    float* Ax0;
    float* h0; float* h1; float* z0; float* z1;
    ushort* h0Thi; ushort* h0Tlo; ushort* h1Thi; ushort* h1Tlo;
    ushort* AH0hi; ushort* AH0lo; ushort* AH1hi; ushort* AH1lo; // AH1 doubles as ARH0
    ushort* ARH1hi; ushort* ARH1lo;
    ushort* RH0Thi; ushort* RH0Tlo; ushort* RH1Thi; ushort* RH1Tlo;
    const ushort* WzrT0; const ushort* WcT0;
    const ushort* WxzrT1; const ushort* WhzrT1;
    const ushort* WxcT1; const ushort* WhcT1;
    BarMem* bar;
};

__device__ void run_phase(const FP& p, int s, int phase, int bid, int G,
                          int tid, ushort* lds) {
    const int L0 = (s < TT);
    const int L1 = (s >= 1);
    if (phase == 0) {
        // AH0 = A@h0T, AH1 = A@h1T, x_job(t=s), head(t=s-2)
        for (int job = bid; job < 360; job += G) {
            if (job < 128)
                g2_job(job, tid, lds, p.Abf, p.h0Thi, p.h0Tlo, p.AH0hi, p.AH0lo);
            else if (job < 256)
                g2_job(job - 128, tid, lds, p.Abf, p.h1Thi, p.h1Tlo, p.AH1hi, p.AH1lo);
            else if (job < 288) {
                if (L0) x_job(job - 256, tid, (float*)lds, (float*)(lds + 64 * LSTR),
                              p.Af, p.x2d, p.mask, p.Ax0, s);
            } else {
                if (s >= 2) head_job(job - 288, tid, p.h1, p.Wout, p.bout, p.out, s - 2);
            }
        }
    } else if (phase == 1) {
        // zr gates (layer0: z0+rh0T; layer1: z1+rh1T)
        const int n0 = L0 ? 256 : 0;
        const int n1 = L1 ? 256 : 0;
        for (int job = bid; job < n0 + n1; job += G) {
            if (job < n0) {
                WSub u{p.AH0hi, p.AH0lo, p.WzrT0, nullptr, nullptr, nullptr, 1,
                       p.b0, 1, 0, p.h0, p.z0, nullptr, p.RH0Thi, p.RH0Tlo};
                wact_job(job, tid, lds, u, 0, p.Ax0, p.Wx0);
            } else {
                WSub u{p.AH0hi, p.AH0lo, p.WxzrT1, p.AH1hi, p.AH1lo, p.WhzrT1, 2,
                       p.b1, 0, 0, p.h1, p.z1, nullptr, p.RH1Thi, p.RH1Tlo};
                wact_job(job - n0, tid, lds, u, 0, p.Ax0, p.Wx0);
            }
        }
    } else if (phase == 2) {
        // ARH0 = A@rh0T (into AH1 alias), ARH1 = A@rh1T
        const int n0 = L0 ? 128 : 0;
        const int n1 = L1 ? 128 : 0;
        for (int job = bid; job < n0 + n1; job += G) {
            if (job < n0)
                g2_job(job, tid, lds, p.Abf, p.RH0Thi, p.RH0Tlo, p.AH1hi, p.AH1lo);
            else
                g2_job(job - n0, tid, lds, p.Abf, p.RH1Thi, p.RH1Tlo, p.ARH1hi, p.ARH1lo);
        }
    } else {
        // c gate + state update (layer0: h0+h0T; layer1: h1+h1T)
        const int n0 = L0 ? 128 : 0;
        const int n1 = L1 ? 128 : 0;
        for (int job = bid; job < n0 + n1; job += G) {
            if (job < n0) {
                WSub u{p.AH1hi, p.AH1lo, p.WcT0, nullptr, nullptr, nullptr, 1,
                       p.b0 + 512, 1, 512, p.h0, p.z0, p.h0, p.h0Thi, p.h0Tlo};
                wact_job(job, tid, lds, u, 1, p.Ax0, p.Wx0);
            } else {
                WSub u{p.ARH1hi, p.ARH1lo, p.WhcT1, p.AH0hi, p.AH0lo, p.WxcT1, 2,
                       p.b1 + 512, 0, 0, p.h1, p.z1, p.h1, p.h1Thi, p.h1Tlo};
                wact_job(job - n0, tid, lds, u, 1, p.Ax0, p.Wx0);
            }
        }
    }
}

// ---------------------------------------------------------------------------
// persistent kernel (cooperative launch) and fallback phase kernels
// ---------------------------------------------------------------------------
__global__ __launch_bounds__(256, 2) void fused_kernel(FP p) {
    __shared__ ushort lds[3 * 64 * LSTR];
    const int tid = threadIdx.x, bid = blockIdx.x, G = gridDim.x;
    const unsigned nb = gridDim.x;
    for (int s = 0; s <= TT; ++s) {
        run_phase(p, s, 0, bid, G, tid, lds);  grid_sync(p.bar, nb);
        run_phase(p, s, 1, bid, G, tid, lds);  grid_sync(p.bar, nb);
        run_phase(p, s, 2, bid, G, tid, lds);  grid_sync(p.bar, nb);
        run_phase(p, s, 3, bid, G, tid, lds);  grid_sync(p.bar, nb);
    }
    for (int job = bid; job < 72; job += G)
        head_job(job, tid, p.h1, p.Wout, p.bout, p.out, TT - 1);
}

__global__ __launch_bounds__(256) void phase_kernel(FP p, int s, int phase) {
    __shared__ ushort lds[3 * 64 * LSTR];
    run_phase(p, s, phase, blockIdx.x, gridDim.x, threadIdx.x, lds);
}

__global__ __launch_bounds__(256) void fhead_kernel(FP p) {
    for (int job = blockIdx.x; job < 72; job += gridDim.x)
        head_job(job, threadIdx.x, p.h1, p.Wout, p.bout, p.out, TT - 1);
}

// ---------------------------------------------------------------------------
extern "C" void kernel_launch(void* const* d_in, const int* in_sizes, int n_in,
                              void* d_out, int out_size, void* d_ws, size_t ws_size,
                              hipStream_t stream) {
    const float* x2d  = (const float*)d_in[0];
    const float* mask = (const float*)d_in[1];
    const float* A    = (const float*)d_in[2];
    const float* Wx0  = (const float*)d_in[3];
    const float* Wh0  = (const float*)d_in[4];
    const float* b0   = (const float*)d_in[5];
    const float* Wx1  = (const float*)d_in[6];
    const float* Wh1  = (const float*)d_in[7];
    const float* b1   = (const float*)d_in[8];
    const float* Wout = (const float*)d_in[9];
    const float* bout = (const float*)d_in[10];
    float* out = (float*)d_out;

    const size_t SZ = (size_t)BN * HH;   // 524288
    float* ws = (float*)d_ws;
    float*  h0    = ws;
    float*  h1    = h0 + SZ;
    ushort* h0Thi = (ushort*)(h1 + SZ);
    ushort* h0Tlo = h0Thi + SZ;
    ushort* h1Thi = h0Tlo + SZ;
    ushort* h1Tlo = h1Thi + SZ;
    float*  z0    = (float*)(h1Tlo + SZ);
    float*  z1    = z0 + SZ;
    float*  Ax0   = z1 + SZ;             // 16384 f
    ushort* AH0hi = (ushort*)(Ax0 + 16384);   // A@h0(s-1) == Ax1 for layer1
    ushort* AH0lo = AH0hi + SZ;
    ushort* AH1hi = AH0lo + SZ;               // A@h1(s-2); reused as ARH0
    ushort* AH1lo = AH1hi + SZ;
    ushort* ARH1hi= AH1lo + SZ;
    ushort* ARH1lo= ARH1hi + SZ;
    ushort* RH0Thi= ARH1lo + SZ;
    ushort* RH0Tlo= RH0Thi + SZ;
    ushort* RH1Thi= RH0Tlo + SZ;
    ushort* RH1Tlo= RH1Thi + SZ;
    ushort* Abf   = RH1Tlo + SZ;         // 65536
    ushort* WzrT0 = Abf + 65536;         // 131072
    ushort* WcT0  = WzrT0 + 131072;      // 65536
    ushort* WxzrT1= WcT0 + 65536;        // 131072
    ushort* WhzrT1= WxzrT1 + 131072;     // 131072
    ushort* WxcT1 = WhzrT1 + 131072;     // 65536
    ushort* WhcT1 = WxcT1 + 65536;       // 65536
    BarMem* bar   = (BarMem*)(WhcT1 + 65536);

    // zero h0,h1 (fp32), the four transposed split buffers, and the barrier
    hipMemsetAsync(h0, 0, (2 * SZ) * sizeof(float) + 4 * SZ * sizeof(ushort), stream);
    hipMemsetAsync(bar, 0, sizeof(BarMem), stream);

    prep_kernel<<<dim3(2560), dim3(256), 0, stream>>>(A, Wh0, Wx1, Wh1,
        Abf, WzrT0, WcT0, WxzrT1, WhzrT1, WxcT1, WhcT1);

    FP p;
    p.Abf = Abf; p.Af = A; p.x2d = x2d; p.mask = mask;
    p.Wx0 = Wx0; p.b0 = b0; p.b1 = b1;
    p.Wout = Wout; p.bout = bout; p.out = out;
    p.Ax0 = Ax0;
    p.h0 = h0; p.h1 = h1; p.z0 = z0; p.z1 = z1;
    p.h0Thi = h0Thi; p.h0Tlo = h0Tlo; p.h1Thi = h1Thi; p.h1Tlo = h1Tlo;
    p.AH0hi = AH0hi; p.AH0lo = AH0lo; p.AH1hi = AH1hi; p.AH1lo = AH1lo;
    p.ARH1hi = ARH1hi; p.ARH1lo = ARH1lo;
    p.RH0Thi = RH0Thi; p.RH0Tlo = RH0Tlo; p.RH1Thi = RH1Thi; p.RH1Tlo = RH1Tlo;
    p.WzrT0 = WzrT0; p.WcT0 = WcT0;
    p.WxzrT1 = WxzrT1; p.WhzrT1 = WhzrT1;
    p.WxcT1 = WxcT1; p.WhcT1 = WhcT1;
    p.bar = bar;

    void* args[] = { &p };
    hipError_t err = hipLaunchCooperativeKernel((void*)fused_kernel, dim3(GRID),
                                                dim3(256), args, 0, stream);
    if (err != hipSuccess) {
        (void)hipGetLastError();
        err = hipLaunchCooperativeKernel((void*)fused_kernel, dim3(256),
                                         dim3(256), args, 0, stream);
    }
    if (err != hipSuccess) {
        (void)hipGetLastError();
        // fallback: round-1-equivalent multi-kernel schedule (verified path)
        for (int s = 0; s <= TT; ++s) {
            const int L0 = (s < TT), L1 = (s >= 1);
            phase_kernel<<<dim3(360), dim3(256), 0, stream>>>(p, s, 0);
            int nz = (L0 ? 256 : 0) + (L1 ? 256 : 0);
            phase_kernel<<<dim3(nz), dim3(256), 0, stream>>>(p, s, 1);
            int nc = (L0 ? 128 : 0) + (L1 ? 128 : 0);
            phase_kernel<<<dim3(nc), dim3(256), 0, stream>>>(p, s, 2);
            phase_kernel<<<dim3(nc), dim3(256), 0, stream>>>(p, s, 3);
        }
        fhead_kernel<<<dim3(72), dim3(256), 0, stream>>>(p);
    }
}

// Round 5
// 8989.888 us; speedup vs baseline: 3.1938x; 3.1938x over previous
//
#include <hip/hip_runtime.h>
#include <math.h>

// Round 5: persistent kernel, 8 independent batch-groups (64 blocks each,
// static bid/64 mapping — no XCC_ID trust). Per-group sense-reversing barrier
// with RELAXED polling and exactly ONE agent release fence (arrive) + ONE
// agent acquire fence (wake) per barrier — placement-independent correct.
// Fixes R3's spin-loop L2-nuke and removes R4's unverifiable XCD assumption.

#define BB 8
#define TT 64
#define NN 256
#define HH 256
#define BN 2048
#define LSTR 72   // LDS row stride in ushorts for a 64-wide K chunk
#define GRID 512

typedef float f32x4 __attribute__((ext_vector_type(4)));
typedef short s16x8 __attribute__((ext_vector_type(8)));

#define MFMA(a, b, c) __builtin_amdgcn_mfma_f32_16x16x32_bf16(a, b, c, 0, 0, 0)

#define SCOPE_AGENT __HIP_MEMORY_SCOPE_AGENT
__device__ __forceinline__ unsigned a_load(unsigned* p) {
    return __hip_atomic_load(p, __ATOMIC_RELAXED, SCOPE_AGENT);
}
__device__ __forceinline__ unsigned a_add(unsigned* p, unsigned v) {
    return __hip_atomic_fetch_add(p, v, __ATOMIC_RELAXED, SCOPE_AGENT);
}
__device__ __forceinline__ void a_store(unsigned* p, unsigned v) {
    __hip_atomic_store(p, v, __ATOMIC_RELAXED, SCOPE_AGENT);
}

__device__ __forceinline__ ushort rne_bf16(float x) {
    unsigned u = __builtin_bit_cast(unsigned, x);
    unsigned r = u + 0x7FFFu + ((u >> 16) & 1u);
    return (ushort)(r >> 16);
}
__device__ __forceinline__ float bf16_f32(ushort h) {
    unsigned u = ((unsigned)h) << 16;
    return __builtin_bit_cast(float, u);
}
__device__ __forceinline__ void split2(float x, ushort& hi, ushort& lo) {
    ushort h = rne_bf16(x);
    hi = h;
    lo = rne_bf16(x - bf16_f32(h));
}

// ---------------------------------------------------------------------------
// group barrier: relaxed poll; one release fence on arrive, one acquire on exit
// ---------------------------------------------------------------------------
struct BarMem { unsigned count; unsigned pad1[15]; unsigned gen; unsigned pad2[15]; };

__device__ __forceinline__ void group_barrier(BarMem* bar, unsigned nb) {
    __syncthreads();                     // all waves: vmcnt drained, stores in L2
    if (threadIdx.x == 0) {
        __builtin_amdgcn_fence(__ATOMIC_RELEASE, "agent");   // wbl2: L2 -> MALL
        unsigned old = a_load(&bar->gen);
        unsigned prev = a_add(&bar->count, 1u);
        if (prev == nb - 1u) {
            a_store(&bar->count, 0u);
            __hip_atomic_fetch_add(&bar->gen, 1u, __ATOMIC_RELEASE, SCOPE_AGENT);
        } else {
            while (a_load(&bar->gen) == old)      // RELAXED poll: no cache ops
                __builtin_amdgcn_s_sleep(2);
        }
        __builtin_amdgcn_fence(__ATOMIC_ACQUIRE, "agent");   // inv L1+L2 once
    }
    __syncthreads();
}

// ---------------------------------------------------------------------------
// prep: round A to bf16; build transposed bf16 weight slabs [Ncols][256]
// ---------------------------------------------------------------------------
__global__ __launch_bounds__(256) void prep_kernel(const float* __restrict__ A,
    const float* __restrict__ Wh0, const float* __restrict__ Wx1,
    const float* __restrict__ Wh1,
    ushort* Abf, ushort* WzrT0, ushort* WcT0, ushort* WxzrT1,
    ushort* WhzrT1, ushort* WxcT1, ushort* WhcT1)
{
    int idx = blockIdx.x * 256 + threadIdx.x;
    if (idx < 65536) { Abf[idx] = rne_bf16(A[idx]); return; }
    int e = idx - 65536;
    ushort* dst; const float* src; int colOff;
    if      (e < 131072) { dst = WzrT0;  src = Wh0; colOff = 0;   }
    else if (e < 196608) { dst = WcT0;   src = Wh0; colOff = 512; e -= 131072; }
    else if (e < 327680) { dst = WxzrT1; src = Wx1; colOff = 0;   e -= 196608; }
    else if (e < 458752) { dst = WhzrT1; src = Wh1; colOff = 0;   e -= 327680; }
    else if (e < 524288) { dst = WxcT1;  src = Wx1; colOff = 512; e -= 458752; }
    else if (e < 589824) { dst = WhcT1;  src = Wh1; colOff = 512; e -= 524288; }
    else return;
    int c = e >> 8, k = e & 255;
    dst[e] = rne_bf16(src[k * 768 + colOff + c]);
}

// ---------------------------------------------------------------------------
// per-batch job bodies (numerics identical to verified R1/R3)
// ---------------------------------------------------------------------------
__device__ void x_job_b(int b, int rt, int tid, float* xs, float* red,
                        const float* Af, const float* x2d, const float* mask,
                        float* Ax0, int t) {
    const float* xbase = x2d + ((size_t)(b * TT + t) * NN) * 6;
    const float* mbase = mask + (size_t)(b * TT + t) * NN;
    {
        int m = tid;
        float mk = mbase[m];
        #pragma unroll
        for (int d = 0; d < 6; ++d) xs[m * 8 + d] = xbase[m * 6 + d] * mk;
    }
    __syncthreads();
    int i = tid & 63, q = tid >> 6;
    const float* arow = Af + (size_t)(rt * 64 + i) * 256 + q * 64;
    float a6[6] = {0.f, 0.f, 0.f, 0.f, 0.f, 0.f};
    for (int m = 0; m < 64; ++m) {
        float a = arow[m];
        const float* xv = &xs[(q * 64 + m) * 8];
        #pragma unroll
        for (int d = 0; d < 6; ++d) a6[d] = fmaf(a, xv[d], a6[d]);
    }
    #pragma unroll
    for (int d = 0; d < 6; ++d) red[(i * 4 + q) * 8 + d] = a6[d];
    __syncthreads();
    for (int idx2 = tid; idx2 < 64 * 6; idx2 += 256) {
        int ii = idx2 / 6, d = idx2 - ii * 6;
        float s = red[(ii * 4 + 0) * 8 + d] + red[(ii * 4 + 1) * 8 + d]
                + red[(ii * 4 + 2) * 8 + d] + red[(ii * 4 + 3) * 8 + d];
        Ax0[(size_t)(b * 256 + rt * 64 + ii) * 8 + d] = s;
    }
    __syncthreads();
}

__device__ void head_job_b(int b, int lb2, int tid, const float* h1,
                           const float* Wout, const float* bout, float* out,
                           int tprev) {
    int g = lb2 * 256 + tid;          // 9 jobs x 256 threads = 2304 = 256*9
    int rl = g / 9, o = g - rl * 9;   // rl in [0,256)
    const float* hr = h1 + (size_t)(b * 256 + rl) * 256;
    float s = bout[o];
    for (int k = 0; k < 256; k += 4) {
        float4 hv = *(const float4*)(hr + k);
        s = fmaf(hv.x, Wout[(k + 0) * 9 + o], s);
        s = fmaf(hv.y, Wout[(k + 1) * 9 + o], s);
        s = fmaf(hv.z, Wout[(k + 2) * 9 + o], s);
        s = fmaf(hv.w, Wout[(k + 3) * 9 + o], s);
    }
    out[((size_t)(b * TT + tprev) * NN + rl) * 9 + o] = s;
}

// g2 job: one 64x64 tile of Y(hi/lo) = A_bf16 @ XT(hi+lo), lb2 in [0,16)
__device__ void g2_job_b(int b, int lb2, int tid, ushort* lds, const ushort* Abf,
                         const ushort* XThi, const ushort* XTlo,
                         ushort* Yhi, ushort* Ylo) {
    ushort* As   = lds;
    ushort* Bshi = lds + 64 * LSTR;
    ushort* Bslo = lds + 2 * 64 * LSTR;
    const int rt = lb2 >> 2, ct = lb2 & 3;

    const int lane = tid & 63, wave = tid >> 6;
    const int wr = wave >> 1, wc = wave & 1;
    const int l15 = lane & 15, q8 = (lane >> 4) << 3;

    f32x4 acc[2][2];
    acc[0][0] = 0.f; acc[0][1] = 0.f; acc[1][0] = 0.f; acc[1][1] = 0.f;

    const int rr = tid >> 2, ko = (tid & 3) << 4;
    const ushort* Asrc = Abf + (size_t)(rt * 64 + rr) * 256 + ko;
    const ushort* Bh   = XThi + (size_t)(b * 256 + ct * 64 + rr) * 256 + ko;
    const ushort* Bl   = XTlo + (size_t)(b * 256 + ct * 64 + rr) * 256 + ko;
    ushort* wA = &As[rr * LSTR + ko];
    ushort* wH = &Bshi[rr * LSTR + ko];
    ushort* wL = &Bslo[rr * LSTR + ko];

    for (int k0 = 0; k0 < 256; k0 += 64) {
        __syncthreads();
        *(uint4*)(wA)     = *(const uint4*)(Asrc + k0);
        *(uint4*)(wA + 8) = *(const uint4*)(Asrc + k0 + 8);
        *(uint4*)(wH)     = *(const uint4*)(Bh + k0);
        *(uint4*)(wH + 8) = *(const uint4*)(Bh + k0 + 8);
        *(uint4*)(wL)     = *(const uint4*)(Bl + k0);
        *(uint4*)(wL + 8) = *(const uint4*)(Bl + k0 + 8);
        __syncthreads();
        #pragma unroll
        for (int sub = 0; sub < 2; ++sub) {
            const int kb = sub * 32 + q8;
            s16x8 a0  = *(const s16x8*)&As[(wr * 32 + l15) * LSTR + kb];
            s16x8 a1  = *(const s16x8*)&As[(wr * 32 + 16 + l15) * LSTR + kb];
            s16x8 bh0 = *(const s16x8*)&Bshi[(wc * 32 + l15) * LSTR + kb];
            s16x8 bh1 = *(const s16x8*)&Bshi[(wc * 32 + 16 + l15) * LSTR + kb];
            s16x8 bl0 = *(const s16x8*)&Bslo[(wc * 32 + l15) * LSTR + kb];
            s16x8 bl1 = *(const s16x8*)&Bslo[(wc * 32 + 16 + l15) * LSTR + kb];
            acc[0][0] = MFMA(a0, bh0, acc[0][0]);
            acc[0][0] = MFMA(a0, bl0, acc[0][0]);
            acc[0][1] = MFMA(a0, bh1, acc[0][1]);
            acc[0][1] = MFMA(a0, bl1, acc[0][1]);
            acc[1][0] = MFMA(a1, bh0, acc[1][0]);
            acc[1][0] = MFMA(a1, bl0, acc[1][0]);
            acc[1][1] = MFMA(a1, bh1, acc[1][1]);
            acc[1][1] = MFMA(a1, bl1, acc[1][1]);
        }
    }
    const int quad = lane >> 4;
    #pragma unroll
    for (int i = 0; i < 2; ++i) {
        #pragma unroll
        for (int j = 0; j < 2; ++j) {
            const int col = ct * 64 + wc * 32 + j * 16 + l15;
            const int m0  = rt * 64 + wr * 32 + i * 16 + quad * 4;
            const size_t base = (size_t)(b * 256 + m0) * 256 + col;
            #pragma unroll
            for (int r = 0; r < 4; ++r) {
                ushort hi, lo;
                split2(acc[i][j][r], hi, lo);
                Yhi[base + (size_t)r * 256] = hi;
                Ylo[base + (size_t)r * 256] = lo;
            }
        }
    }
    __syncthreads();
}

// wact job: gate GEMM + epilogue
struct WSub {
    const ushort* Lhi0; const ushort* Llo0; const ushort* RT0;
    const ushort* Lhi1; const ushort* Llo1; const ushort* RT1;
    int ngemm;
    const float* bias;
    int useK6; int wxColOff;
    const float* h;
    float* z;
    float* hOut;
    ushort* Thi; ushort* Tlo;
};

__device__ void wact_job_b(int b, int lb2, int tid, ushort* lds, const WSub& u,
                           int mode, const float* Ax0, const float* Wx0) {
    ushort* Ashi = lds;
    ushort* Aslo = lds + 64 * LSTR;
    ushort* Bs   = lds + 2 * 64 * LSTR;
    int rt, ct;
    if (mode == 0) { rt = (lb2 >> 3) & 3; ct = lb2 & 7; }
    else           { rt = (lb2 >> 2) & 3; ct = lb2 & 3; }

    const int lane = tid & 63, wave = tid >> 6;
    const int wr = wave >> 1, wc = wave & 1;
    const int l15 = lane & 15, q8 = (lane >> 4) << 3;

    f32x4 acc[2][2];
    acc[0][0] = 0.f; acc[0][1] = 0.f; acc[1][0] = 0.f; acc[1][1] = 0.f;

    const int rr = tid >> 2, ko = (tid & 3) << 4;
    for (int g = 0; g < u.ngemm; ++g) {
        const ushort* Lh = (g ? u.Lhi1 : u.Lhi0) + (size_t)(b * 256 + rt * 64 + rr) * 256 + ko;
        const ushort* Ll = (g ? u.Llo1 : u.Llo0) + (size_t)(b * 256 + rt * 64 + rr) * 256 + ko;
        const ushort* Rt = (g ? u.RT1  : u.RT0 ) + (size_t)(ct * 64 + rr) * 256 + ko;
        ushort* wA = &Ashi[rr * LSTR + ko];
        ushort* wL = &Aslo[rr * LSTR + ko];
        ushort* wB = &Bs[rr * LSTR + ko];
        for (int k0 = 0; k0 < 256; k0 += 64) {
            __syncthreads();
            *(uint4*)(wA)     = *(const uint4*)(Lh + k0);
            *(uint4*)(wA + 8) = *(const uint4*)(Lh + k0 + 8);
            *(uint4*)(wL)     = *(const uint4*)(Ll + k0);
            *(uint4*)(wL + 8) = *(const uint4*)(Ll + k0 + 8);
            *(uint4*)(wB)     = *(const uint4*)(Rt + k0);
            *(uint4*)(wB + 8) = *(const uint4*)(Rt + k0 + 8);
            __syncthreads();
            #pragma unroll
            for (int sub = 0; sub < 2; ++sub) {
                const int kb = sub * 32 + q8;
                s16x8 ah0 = *(const s16x8*)&Ashi[(wr * 32 + l15) * LSTR + kb];
                s16x8 ah1 = *(const s16x8*)&Ashi[(wr * 32 + 16 + l15) * LSTR + kb];
                s16x8 al0 = *(const s16x8*)&Aslo[(wr * 32 + l15) * LSTR + kb];
                s16x8 al1 = *(const s16x8*)&Aslo[(wr * 32 + 16 + l15) * LSTR + kb];
                s16x8 b0  = *(const s16x8*)&Bs[(wc * 32 + l15) * LSTR + kb];
                s16x8 b1  = *(const s16x8*)&Bs[(wc * 32 + 16 + l15) * LSTR + kb];
                acc[0][0] = MFMA(ah0, b0, acc[0][0]);
                acc[0][0] = MFMA(al0, b0, acc[0][0]);
                acc[0][1] = MFMA(ah0, b1, acc[0][1]);
                acc[0][1] = MFMA(al0, b1, acc[0][1]);
                acc[1][0] = MFMA(ah1, b0, acc[1][0]);
                acc[1][0] = MFMA(al1, b0, acc[1][0]);
                acc[1][1] = MFMA(ah1, b1, acc[1][1]);
                acc[1][1] = MFMA(al1, b1, acc[1][1]);
            }
        }
    }

    const int quad = lane >> 4;
    const int m0base = rt * 64 + wr * 32;
    int colg[2];
    #pragma unroll
    for (int j = 0; j < 2; ++j) colg[j] = ct * 64 + wc * 32 + j * 16 + l15;
    float bv[2] = { u.bias[colg[0]], u.bias[colg[1]] };
    float v[2][2][4];
    #pragma unroll
    for (int i = 0; i < 2; ++i)
        #pragma unroll
        for (int j = 0; j < 2; ++j)
            #pragma unroll
            for (int r = 0; r < 4; ++r)
                v[i][j][r] = acc[i][j][r] + bv[j];

    if (u.useK6) {
        float w6[2][6];
        #pragma unroll
        for (int j = 0; j < 2; ++j)
            #pragma unroll
            for (int d = 0; d < 6; ++d)
                w6[j][d] = Wx0[d * 768 + u.wxColOff + colg[j]];
        #pragma unroll
        for (int i = 0; i < 2; ++i) {
            #pragma unroll
            for (int r = 0; r < 4; ++r) {
                int row = b * 256 + m0base + i * 16 + quad * 4 + r;
                const float* ax = Ax0 + (size_t)row * 8;
                float a0 = ax[0], a1 = ax[1], a2 = ax[2], a3 = ax[3], a4 = ax[4], a5 = ax[5];
                #pragma unroll
                for (int j = 0; j < 2; ++j)
                    v[i][j][r] += a0 * w6[j][0] + a1 * w6[j][1] + a2 * w6[j][2]
                                + a3 * w6[j][3] + a4 * w6[j][4] + a5 * w6[j][5];
            }
        }
    }

    if (mode == 0) {
        if (ct < 4) {
            #pragma unroll
            for (int i = 0; i < 2; ++i)
                #pragma unroll
                for (int r = 0; r < 4; ++r) {
                    int row = b * 256 + m0base + i * 16 + quad * 4 + r;
                    #pragma unroll
                    for (int j = 0; j < 2; ++j)
                        u.z[(size_t)row * 256 + colg[j]] = 1.f / (1.f + __expf(-v[i][j][r]));
                }
        } else {
            #pragma unroll
            for (int i = 0; i < 2; ++i) {
                int m0 = m0base + i * 16 + quad * 4;
                #pragma unroll
                for (int j = 0; j < 2; ++j) {
                    int colp = colg[j] - 256;
                    ushort hi4[4], lo4[4];
                    #pragma unroll
                    for (int r = 0; r < 4; ++r) {
                        int row = b * 256 + m0 + r;
                        float s = 1.f / (1.f + __expf(-v[i][j][r]));
                        float rh = s * u.h[(size_t)row * 256 + colp];
                        split2(rh, hi4[r], lo4[r]);
                    }
                    size_t off = (size_t)b * 65536 + (size_t)colp * 256 + m0;
                    *(ushort4*)&u.Thi[off] = make_ushort4(hi4[0], hi4[1], hi4[2], hi4[3]);
                    *(ushort4*)&u.Tlo[off] = make_ushort4(lo4[0], lo4[1], lo4[2], lo4[3]);
                }
            }
        }
    } else {
        #pragma unroll
        for (int i = 0; i < 2; ++i) {
            int m0 = m0base + i * 16 + quad * 4;
            #pragma unroll
            for (int j = 0; j < 2; ++j) {
                ushort hi4[4], lo4[4];
                #pragma unroll
                for (int r = 0; r < 4; ++r) {
                    int row = b * 256 + m0 + r;
                    size_t gi = (size_t)row * 256 + colg[j];
                    float c = tanhf(v[i][j][r]);
                    float zz = u.z[gi];
                    float hh = u.h[gi];
                    float hn = zz * hh + (1.f - zz) * c;
                    u.hOut[gi] = hn;
                    split2(hn, hi4[r], lo4[r]);
                }
                size_t off = (size_t)b * 65536 + (size_t)colg[j] * 256 + m0;
                *(ushort4*)&u.Thi[off] = make_ushort4(hi4[0], hi4[1], hi4[2], hi4[3]);
                *(ushort4*)&u.Tlo[off] = make_ushort4(lo4[0], lo4[1], lo4[2], lo4[3]);
            }
        }
    }
    __syncthreads();
}

// ---------------------------------------------------------------------------
// job dispatcher: phase x (batch, local job id)
// jobs/phase: P0=45 (16 AH0 + 16 AH1 + 4 x + 9 head), P1=64, P2=32, P3=32
// ---------------------------------------------------------------------------
struct FP {
    const ushort* Abf;
    const float* Af; const float* x2d; const float* mask;
    const float* Wx0; const float* b0; const float* b1;
    const float* Wout; const float* bout; float* out;
    float* Ax0;
    float* h0; float* h1; float* z0; float* z1;
    ushort* h0Thi; ushort* h0Tlo; ushort* h1Thi; ushort* h1Tlo;
    ushort* AH0hi; ushort* AH0lo; ushort* AH1hi; ushort* AH1lo; // AH1 doubles as ARH0
    ushort* ARH1hi; ushort* ARH1lo;
    ushort* RH0Thi; ushort* RH0Tlo; ushort* RH1Thi; ushort* RH1Tlo;
    const ushort* WzrT0; const ushort* WcT0;
    const ushort* WxzrT1; const ushort* WhzrT1;
    const ushort* WxcT1; const ushort* WhcT1;
    BarMem* bars;       // [0..7] per-batch-group
};

__device__ __forceinline__ int phase_jobs(int ph) {
    return (ph == 0) ? 45 : (ph == 1) ? 64 : 32;
}

__device__ void run_job(const FP& p, int s, int ph, int b, int j, int tid,
                        ushort* lds) {
    const int L0 = (s < TT), L1 = (s >= 1);
    if (ph == 0) {
        if (j < 16)
            g2_job_b(b, j, tid, lds, p.Abf, p.h0Thi, p.h0Tlo, p.AH0hi, p.AH0lo);
        else if (j < 32) {
            if (L1) g2_job_b(b, j - 16, tid, lds, p.Abf, p.h1Thi, p.h1Tlo,
                             p.AH1hi, p.AH1lo);
        } else if (j < 36) {
            if (L0) x_job_b(b, j - 32, tid, (float*)lds, (float*)(lds + 64 * LSTR),
                            p.Af, p.x2d, p.mask, p.Ax0, s);
        } else {
            if (s >= 2) head_job_b(b, j - 36, tid, p.h1, p.Wout, p.bout, p.out, s - 2);
        }
    } else if (ph == 1) {
        if (j < 32) {
            if (L0) {
                WSub u{p.AH0hi, p.AH0lo, p.WzrT0, nullptr, nullptr, nullptr, 1,
                       p.b0, 1, 0, p.h0, p.z0, nullptr, p.RH0Thi, p.RH0Tlo};
                wact_job_b(b, j, tid, lds, u, 0, p.Ax0, p.Wx0);
            }
        } else {
            if (L1) {
                WSub u{p.AH0hi, p.AH0lo, p.WxzrT1, p.AH1hi, p.AH1lo, p.WhzrT1, 2,
                       p.b1, 0, 0, p.h1, p.z1, nullptr, p.RH1Thi, p.RH1Tlo};
                wact_job_b(b, j - 32, tid, lds, u, 0, p.Ax0, p.Wx0);
            }
        }
    } else if (ph == 2) {
        if (j < 16) {
            if (L0) g2_job_b(b, j, tid, lds, p.Abf, p.RH0Thi, p.RH0Tlo,
                             p.AH1hi, p.AH1lo);   // ARH0 aliases AH1
        } else {
            if (L1) g2_job_b(b, j - 16, tid, lds, p.Abf, p.RH1Thi, p.RH1Tlo,
                             p.ARH1hi, p.ARH1lo);
        }
    } else {
        if (j < 16) {
            if (L0) {
                WSub u{p.AH1hi, p.AH1lo, p.WcT0, nullptr, nullptr, nullptr, 1,
                       p.b0 + 512, 1, 512, p.h0, p.z0, p.h0, p.h0Thi, p.h0Tlo};
                wact_job_b(b, j, tid, lds, u, 1, p.Ax0, p.Wx0);
            }
        } else {
            if (L1) {
                WSub u{p.ARH1hi, p.ARH1lo, p.WhcT1, p.AH0hi, p.AH0lo, p.WxcT1, 2,
                       p.b1 + 512, 0, 0, p.h1, p.z1, p.h1, p.h1Thi, p.h1Tlo};
                wact_job_b(b, j - 16, tid, lds, u, 1, p.Ax0, p.Wx0);
            }
        }
    }
}

// ---------------------------------------------------------------------------
// persistent kernel: 8 independent batch-groups, each nG = gridDim/8 blocks
// ---------------------------------------------------------------------------
__global__ __launch_bounds__(256, 2) void fused_kernel(FP p) {
    __shared__ ushort lds[3 * 64 * LSTR];
    const int tid = threadIdx.x, bid = blockIdx.x, G = gridDim.x;
    const int nG = G >> 3;            // blocks per group (G divisible by 8)
    const int b  = bid / nG;          // batch = group id
    const int w  = bid - b * nG;      // index within group
    BarMem* bar = &p.bars[b];

    for (int s = 0; s <= TT; ++s) {
        for (int ph = 0; ph < 4; ++ph) {
            const int nj = phase_jobs(ph);
            for (int j = w; j < nj; j += nG)
                run_job(p, s, ph, b, j, tid, lds);
            group_barrier(bar, (unsigned)nG);
        }
    }
    for (int j = w; j < 9; j += nG)
        head_job_b(b, j, tid, p.h1, p.Wout, p.bout, p.out, TT - 1);
}

// multi-kernel fallback (natural barriers at dispatch boundaries)
__global__ __launch_bounds__(256) void phase_kernel(FP p, int s, int ph) {
    __shared__ ushort lds[3 * 64 * LSTR];
    const int nj = phase_jobs(ph);
    for (int bb = 0; bb < 8; ++bb)
        for (int j = blockIdx.x; j < nj; j += gridDim.x)
            run_job(p, s, ph, bb, j, threadIdx.x, lds);
}

__global__ __launch_bounds__(256) void fhead_kernel(FP p) {
    for (int bb = 0; bb < 8; ++bb)
        for (int j = blockIdx.x; j < 9; j += gridDim.x)
            head_job_b(bb, j, threadIdx.x, p.h1, p.Wout, p.bout, p.out, TT - 1);
}

// ---------------------------------------------------------------------------
extern "C" void kernel_launch(void* const* d_in, const int* in_sizes, int n_in,
                              void* d_out, int out_size, void* d_ws, size_t ws_size,
                              hipStream_t stream) {
    const float* x2d  = (const float*)d_in[0];
    const float* mask = (const float*)d_in[1];
    const float* A    = (const float*)d_in[2];
    const float* Wx0  = (const float*)d_in[3];
    const float* Wh0  = (const float*)d_in[4];
    const float* b0   = (const float*)d_in[5];
    const float* Wx1  = (const float*)d_in[6];
    const float* Wh1  = (const float*)d_in[7];
    const float* b1   = (const float*)d_in[8];
    const float* Wout = (const float*)d_in[9];
    const float* bout = (const float*)d_in[10];
    float* out = (float*)d_out;

    const size_t SZ = (size_t)BN * HH;   // 524288
    float* ws = (float*)d_ws;
    float*  h0    = ws;
    float*  h1    = h0 + SZ;
    ushort* h0Thi = (ushort*)(h1 + SZ);
    ushort* h0Tlo = h0Thi + SZ;
    ushort* h1Thi = h0Tlo + SZ;
    ushort* h1Tlo = h1Thi + SZ;
    float*  z0    = (float*)(h1Tlo + SZ);
    float*  z1    = z0 + SZ;
    float*  Ax0   = z1 + SZ;             // 16384 f
    ushort* AH0hi = (ushort*)(Ax0 + 16384);
    ushort* AH0lo = AH0hi + SZ;
    ushort* AH1hi = AH0lo + SZ;          // doubles as ARH0 after phase 1
    ushort* AH1lo = AH1hi + SZ;
    ushort* ARH1hi= AH1lo + SZ;
    ushort* ARH1lo= ARH1hi + SZ;
    ushort* RH0Thi= ARH1lo + SZ;
    ushort* RH0Tlo= RH0Thi + SZ;
    ushort* RH1Thi= RH0Tlo + SZ;
    ushort* RH1Tlo= RH1Thi + SZ;
    ushort* Abf   = RH1Tlo + SZ;         // 65536
    ushort* WzrT0 = Abf + 65536;         // 131072
    ushort* WcT0  = WzrT0 + 131072;      // 65536
    ushort* WxzrT1= WcT0 + 65536;        // 131072
    ushort* WhzrT1= WxzrT1 + 131072;     // 131072
    ushort* WxcT1 = WhzrT1 + 131072;     // 65536
    ushort* WhcT1 = WxcT1 + 65536;       // 65536
    BarMem* bars  = (BarMem*)(WhcT1 + 65536);      // 8 group barriers

    hipMemsetAsync(h0, 0, (2 * SZ) * sizeof(float) + 4 * SZ * sizeof(ushort), stream);
    hipMemsetAsync(bars, 0, 8 * sizeof(BarMem), stream);

    prep_kernel<<<dim3(2560), dim3(256), 0, stream>>>(A, Wh0, Wx1, Wh1,
        Abf, WzrT0, WcT0, WxzrT1, WhzrT1, WxcT1, WhcT1);

    FP p;
    p.Abf = Abf; p.Af = A; p.x2d = x2d; p.mask = mask;
    p.Wx0 = Wx0; p.b0 = b0; p.b1 = b1;
    p.Wout = Wout; p.bout = bout; p.out = out;
    p.Ax0 = Ax0;
    p.h0 = h0; p.h1 = h1; p.z0 = z0; p.z1 = z1;
    p.h0Thi = h0Thi; p.h0Tlo = h0Tlo; p.h1Thi = h1Thi; p.h1Tlo = h1Tlo;
    p.AH0hi = AH0hi; p.AH0lo = AH0lo; p.AH1hi = AH1hi; p.AH1lo = AH1lo;
    p.ARH1hi = ARH1hi; p.ARH1lo = ARH1lo;
    p.RH0Thi = RH0Thi; p.RH0Tlo = RH0Tlo; p.RH1Thi = RH1Thi; p.RH1Tlo = RH1Tlo;
    p.WzrT0 = WzrT0; p.WcT0 = WcT0;
    p.WxzrT1 = WxzrT1; p.WhzrT1 = WhzrT1;
    p.WxcT1 = WxcT1; p.WhcT1 = WhcT1;
    p.bars = bars;

    void* args[] = { &p };
    hipError_t err = hipLaunchCooperativeKernel((void*)fused_kernel, dim3(GRID),
                                                dim3(256), args, 0, stream);
    if (err != hipSuccess) {
        (void)hipGetLastError();
        err = hipLaunchCooperativeKernel((void*)fused_kernel, dim3(256),
                                         dim3(256), args, 0, stream);
    }
    if (err != hipSuccess) {
        (void)hipGetLastError();
        for (int s = 0; s <= TT; ++s)
            for (int ph = 0; ph < 4; ++ph)
                phase_kernel<<<dim3(512), dim3(256), 0, stream>>>(p, s, ph);
        fhead_kernel<<<dim3(72), dim3(256), 0, stream>>>(p);
    }
}

// Round 8
// 3298.844 us; speedup vs baseline: 8.7036x; 2.7252x over previous
//
#include <hip/hip_runtime.h>
#include <math.h>

// Round 8: revert to the VERIFIED Round-1 multi-kernel pipelined schedule
// (passed, 3350 us; kernel boundaries give cross-block coherence for free).
// Persistent-kernel branch abandoned: R6/R7's bit-identical failures prove
// sc0/sc1 loads do NOT bypass L2 on gfx950, and the correct variant (R5,
// full agent fences) measured 9 ms. Single in-kernel change vs Round 1:
// register double-buffered global->LDS staging (prefetch chunk k+1 after the
// post-write barrier, hiding ~300-900cy load latency under chunk k's MFMAs).
// Numerics bit-identical to Round 1.

#define BB 8
#define TT 64
#define NN 256
#define HH 256
#define BN 2048
#define LSTR 72   // LDS row stride in ushorts for a 64-wide K chunk

typedef float f32x4 __attribute__((ext_vector_type(4)));
typedef short s16x8 __attribute__((ext_vector_type(8)));

#define MFMA(a, b, c) __builtin_amdgcn_mfma_f32_16x16x32_bf16(a, b, c, 0, 0, 0)

__device__ __forceinline__ ushort rne_bf16(float x) {
    unsigned u = __builtin_bit_cast(unsigned, x);
    unsigned r = u + 0x7FFFu + ((u >> 16) & 1u);
    return (ushort)(r >> 16);
}
__device__ __forceinline__ float bf16_f32(ushort h) {
    unsigned u = ((unsigned)h) << 16;
    return __builtin_bit_cast(float, u);
}
__device__ __forceinline__ void split2(float x, ushort& hi, ushort& lo) {
    ushort h = rne_bf16(x);
    hi = h;
    lo = rne_bf16(x - bf16_f32(h));
}

// ---------------------------------------------------------------------------
// prep: round A to bf16; build transposed bf16 weight slabs [Ncols][256]
// ---------------------------------------------------------------------------
__global__ __launch_bounds__(256) void prep_kernel(const float* __restrict__ A,
    const float* __restrict__ Wh0, const float* __restrict__ Wx1,
    const float* __restrict__ Wh1,
    ushort* Abf, ushort* WzrT0, ushort* WcT0, ushort* WxzrT1,
    ushort* WhzrT1, ushort* WxcT1, ushort* WhcT1)
{
    int idx = blockIdx.x * 256 + threadIdx.x;
    if (idx < 65536) { Abf[idx] = rne_bf16(A[idx]); return; }
    int e = idx - 65536;
    ushort* dst; const float* src; int colOff;
    if      (e < 131072) { dst = WzrT0;  src = Wh0; colOff = 0;   }
    else if (e < 196608) { dst = WcT0;   src = Wh0; colOff = 512; e -= 131072; }
    else if (e < 327680) { dst = WxzrT1; src = Wx1; colOff = 0;   e -= 196608; }
    else if (e < 458752) { dst = WhzrT1; src = Wh1; colOff = 0;   e -= 327680; }
    else if (e < 524288) { dst = WxcT1;  src = Wx1; colOff = 512; e -= 458752; }
    else if (e < 589824) { dst = WhcT1;  src = Wh1; colOff = 512; e -= 524288; }
    else return;
    int c = e >> 8, k = e & 255;
    dst[e] = rne_bf16(src[k * 768 + colOff + c]);
}

// ---------------------------------------------------------------------------
// device helpers: exact fp32 x-job (Ax0 = A@(x_t*mask)) and head
// ---------------------------------------------------------------------------
__device__ void x_job(int lb, int tid, float* xs, float* red, const float* Af,
                      const float* x2d, const float* mask, float* Ax0, int t) {
    int b = lb >> 2, rt = lb & 3;
    const float* xbase = x2d + ((size_t)(b * TT + t) * NN) * 6;
    const float* mbase = mask + (size_t)(b * TT + t) * NN;
    {
        int m = tid;
        float mk = mbase[m];
        #pragma unroll
        for (int d = 0; d < 6; ++d) xs[m * 8 + d] = xbase[m * 6 + d] * mk;
    }
    __syncthreads();
    int i = tid & 63, q = tid >> 6;
    const float* arow = Af + (size_t)(rt * 64 + i) * 256 + q * 64;
    float a6[6] = {0.f, 0.f, 0.f, 0.f, 0.f, 0.f};
    for (int m = 0; m < 64; ++m) {
        float a = arow[m];
        const float* xv = &xs[(q * 64 + m) * 8];
        #pragma unroll
        for (int d = 0; d < 6; ++d) a6[d] = fmaf(a, xv[d], a6[d]);
    }
    #pragma unroll
    for (int d = 0; d < 6; ++d) red[(i * 4 + q) * 8 + d] = a6[d];
    __syncthreads();
    for (int idx2 = tid; idx2 < 64 * 6; idx2 += 256) {
        int ii = idx2 / 6, d = idx2 - ii * 6;
        float s = red[(ii * 4 + 0) * 8 + d] + red[(ii * 4 + 1) * 8 + d]
                + red[(ii * 4 + 2) * 8 + d] + red[(ii * 4 + 3) * 8 + d];
        Ax0[(size_t)(b * 256 + rt * 64 + ii) * 8 + d] = s;
    }
}

__device__ void head_job(int lb, int tid, const float* h1, const float* Wout,
                         const float* bout, float* out, int tprev) {
    int g = lb * 256 + tid;
    int row = g / 9, o = g - row * 9;
    if (row >= BN) return;
    const float* hr = h1 + (size_t)row * 256;
    float s = bout[o];
    for (int k = 0; k < 256; k += 4) {
        float4 hv = *(const float4*)(hr + k);
        s = fmaf(hv.x, Wout[(k + 0) * 9 + o], s);
        s = fmaf(hv.y, Wout[(k + 1) * 9 + o], s);
        s = fmaf(hv.z, Wout[(k + 2) * 9 + o], s);
        s = fmaf(hv.w, Wout[(k + 3) * 9 + o], s);
    }
    int b = row >> 8, n = row & 255;
    out[((size_t)(b * TT + tprev) * NN + n) * 9 + o] = s;
}

__global__ __launch_bounds__(256) void head_kernel(const float* __restrict__ h1,
    const float* __restrict__ Wout, const float* __restrict__ bout,
    float* __restrict__ out, int tprev)
{
    head_job(blockIdx.x, threadIdx.x, h1, Wout, bout, out, tprev);
}

// ---------------------------------------------------------------------------
// g2: A-apply via MFMA.  Y(hi/lo split, [2048][256]) = A_bf16 @ XT(hi+lo)
// Register double-buffered staging: prefetch chunk k+1 after the post-write
// barrier so its global latency hides under chunk k's MFMAs.
// ---------------------------------------------------------------------------
struct G2P {
    const ushort* Abf;
    const ushort* XThi0; const ushort* XTlo0; ushort* Yhi0; ushort* Ylo0;
    const ushort* XThi1; const ushort* XTlo1; ushort* Yhi1; ushort* Ylo1;
    int nJobs;
    int doX;
    int headT;   // -1 = skip
    int t;
    const float* Af; const float* x2d; const float* mask; float* Ax0;
    const float* h1; const float* Wout; const float* bout; float* out;
};

__global__ __launch_bounds__(256) void g2_kernel(G2P p) {
    __shared__ ushort lds[3 * 64 * LSTR];
    ushort* As   = lds;
    ushort* Bshi = lds + 64 * LSTR;
    ushort* Bslo = lds + 2 * 64 * LSTR;
    const int tid = threadIdx.x;
    const int bid = blockIdx.x;
    const int mainB = p.nJobs * 128;

    if (bid < mainB) {
        const int job = bid >> 7, lb = bid & 127;
        const ushort* XThi = job ? p.XThi1 : p.XThi0;
        const ushort* XTlo = job ? p.XTlo1 : p.XTlo0;
        ushort* Yhi = job ? p.Yhi1 : p.Yhi0;
        ushort* Ylo = job ? p.Ylo1 : p.Ylo0;
        const int b = lb >> 4, rt = (lb >> 2) & 3, ct = lb & 3;

        const int lane = tid & 63, wave = tid >> 6;
        const int wr = wave >> 1, wc = wave & 1;
        const int l15 = lane & 15, q8 = (lane >> 4) << 3;

        f32x4 acc[2][2];
        acc[0][0] = 0.f; acc[0][1] = 0.f; acc[1][0] = 0.f; acc[1][1] = 0.f;

        const int rr = tid >> 2, ko = (tid & 3) << 4;
        const ushort* Asrc = p.Abf + (size_t)(rt * 64 + rr) * 256 + ko;
        const ushort* Bh   = XThi + (size_t)(b * 256 + ct * 64 + rr) * 256 + ko;
        const ushort* Bl   = XTlo + (size_t)(b * 256 + ct * 64 + rr) * 256 + ko;
        ushort* wA = &As[rr * LSTR + ko];
        ushort* wH = &Bshi[rr * LSTR + ko];
        ushort* wL = &Bslo[rr * LSTR + ko];

        // preload chunk 0 into registers
        uint4 rA0 = *(const uint4*)(Asrc);
        uint4 rA1 = *(const uint4*)(Asrc + 8);
        uint4 rH0 = *(const uint4*)(Bh);
        uint4 rH1 = *(const uint4*)(Bh + 8);
        uint4 rL0 = *(const uint4*)(Bl);
        uint4 rL1 = *(const uint4*)(Bl + 8);

        for (int k0 = 0; k0 < 256; k0 += 64) {
            __syncthreads();
            *(uint4*)(wA)     = rA0;
            *(uint4*)(wA + 8) = rA1;
            *(uint4*)(wH)     = rH0;
            *(uint4*)(wH + 8) = rH1;
            *(uint4*)(wL)     = rL0;
            *(uint4*)(wL + 8) = rL1;
            __syncthreads();
            if (k0 < 192) {   // prefetch next chunk; latency hides under MFMAs
                rA0 = *(const uint4*)(Asrc + k0 + 64);
                rA1 = *(const uint4*)(Asrc + k0 + 72);
                rH0 = *(const uint4*)(Bh + k0 + 64);
                rH1 = *(const uint4*)(Bh + k0 + 72);
                rL0 = *(const uint4*)(Bl + k0 + 64);
                rL1 = *(const uint4*)(Bl + k0 + 72);
            }
            #pragma unroll
            for (int sub = 0; sub < 2; ++sub) {
                const int kb = sub * 32 + q8;
                s16x8 a0  = *(const s16x8*)&As[(wr * 32 + l15) * LSTR + kb];
                s16x8 a1  = *(const s16x8*)&As[(wr * 32 + 16 + l15) * LSTR + kb];
                s16x8 bh0 = *(const s16x8*)&Bshi[(wc * 32 + l15) * LSTR + kb];
                s16x8 bh1 = *(const s16x8*)&Bshi[(wc * 32 + 16 + l15) * LSTR + kb];
                s16x8 bl0 = *(const s16x8*)&Bslo[(wc * 32 + l15) * LSTR + kb];
                s16x8 bl1 = *(const s16x8*)&Bslo[(wc * 32 + 16 + l15) * LSTR + kb];
                acc[0][0] = MFMA(a0, bh0, acc[0][0]);
                acc[0][0] = MFMA(a0, bl0, acc[0][0]);
                acc[0][1] = MFMA(a0, bh1, acc[0][1]);
                acc[0][1] = MFMA(a0, bl1, acc[0][1]);
                acc[1][0] = MFMA(a1, bh0, acc[1][0]);
                acc[1][0] = MFMA(a1, bl0, acc[1][0]);
                acc[1][1] = MFMA(a1, bh1, acc[1][1]);
                acc[1][1] = MFMA(a1, bl1, acc[1][1]);
            }
        }
        const int quad = lane >> 4;
        #pragma unroll
        for (int i = 0; i < 2; ++i) {
            #pragma unroll
            for (int j = 0; j < 2; ++j) {
                const int col = ct * 64 + wc * 32 + j * 16 + l15;
                const int m0  = rt * 64 + wr * 32 + i * 16 + quad * 4;
                const size_t base = (size_t)(b * 256 + m0) * 256 + col;
                #pragma unroll
                for (int r = 0; r < 4; ++r) {
                    ushort hi, lo;
                    split2(acc[i][j][r], hi, lo);
                    Yhi[base + (size_t)r * 256] = hi;
                    Ylo[base + (size_t)r * 256] = lo;
                }
            }
        }
    } else if (bid < mainB + 32) {
        if (p.doX)
            x_job(bid - mainB, tid, (float*)lds, (float*)(lds + 64 * LSTR),
                  p.Af, p.x2d, p.mask, p.Ax0, p.t);
    } else {
        if (p.headT >= 0)
            head_job(bid - mainB - 32, tid, p.h1, p.Wout, p.bout, p.out, p.headT);
    }
}

// ---------------------------------------------------------------------------
// wact: gate GEMM (left = dynamic split pair, right = static bf16 WT) + epilogue
// Two sub-dispatches (layer0 / layer1) selected by block id vs nBlk0.
// mode 0 (zr): 8 col-tiles; ct<4 -> z=sigmoid; ct>=4 -> rhT split pair
// mode 1 (c):  4 col-tiles; h' = z*h+(1-z)*tanh(g); writes h fp32 + hT pair
// ---------------------------------------------------------------------------
struct WSub {
    const ushort* Lhi0; const ushort* Llo0; const ushort* RT0;
    const ushort* Lhi1; const ushort* Llo1; const ushort* RT1;
    int ngemm;
    const float* bias;
    int useK6; int wxColOff;
    const float* h;
    float* z;
    float* hOut;
    ushort* Thi; ushort* Tlo;
};

struct WAP2 {
    WSub u0, u1;
    int nBlk0;
    int mode;
    const float* Ax0; const float* Wx0;
};

__global__ __launch_bounds__(256) void wact_kernel(WAP2 p) {
    __shared__ ushort lds[3 * 64 * LSTR];
    ushort* Ashi = lds;
    ushort* Aslo = lds + 64 * LSTR;
    ushort* Bs   = lds + 2 * 64 * LSTR;
    const int tid = threadIdx.x;
    const int bid = blockIdx.x;
    const int isU1 = (bid >= p.nBlk0);
    const WSub u = isU1 ? p.u1 : p.u0;
    const int lb = isU1 ? bid - p.nBlk0 : bid;
    int b, rt, ct;
    if (p.mode == 0) { b = lb >> 5; rt = (lb >> 3) & 3; ct = lb & 7; }
    else             { b = lb >> 4; rt = (lb >> 2) & 3; ct = lb & 3; }

    const int lane = tid & 63, wave = tid >> 6;
    const int wr = wave >> 1, wc = wave & 1;
    const int l15 = lane & 15, q8 = (lane >> 4) << 3;

    f32x4 acc[2][2];
    acc[0][0] = 0.f; acc[0][1] = 0.f; acc[1][0] = 0.f; acc[1][1] = 0.f;

    const int rr = tid >> 2, ko = (tid & 3) << 4;
    for (int g = 0; g < u.ngemm; ++g) {
        const ushort* Lh = (g ? u.Lhi1 : u.Lhi0) + (size_t)(b * 256 + rt * 64 + rr) * 256 + ko;
        const ushort* Ll = (g ? u.Llo1 : u.Llo0) + (size_t)(b * 256 + rt * 64 + rr) * 256 + ko;
        const ushort* Rt = (g ? u.RT1  : u.RT0 ) + (size_t)(ct * 64 + rr) * 256 + ko;
        ushort* wA = &Ashi[rr * LSTR + ko];
        ushort* wL = &Aslo[rr * LSTR + ko];
        ushort* wB = &Bs[rr * LSTR + ko];

        // preload chunk 0 of this gemm
        uint4 rA0 = *(const uint4*)(Lh);
        uint4 rA1 = *(const uint4*)(Lh + 8);
        uint4 rL0 = *(const uint4*)(Ll);
        uint4 rL1 = *(const uint4*)(Ll + 8);
        uint4 rB0 = *(const uint4*)(Rt);
        uint4 rB1 = *(const uint4*)(Rt + 8);

        for (int k0 = 0; k0 < 256; k0 += 64) {
            __syncthreads();
            *(uint4*)(wA)     = rA0;
            *(uint4*)(wA + 8) = rA1;
            *(uint4*)(wL)     = rL0;
            *(uint4*)(wL + 8) = rL1;
            *(uint4*)(wB)     = rB0;
            *(uint4*)(wB + 8) = rB1;
            __syncthreads();
            if (k0 < 192) {   // prefetch next chunk
                rA0 = *(const uint4*)(Lh + k0 + 64);
                rA1 = *(const uint4*)(Lh + k0 + 72);
                rL0 = *(const uint4*)(Ll + k0 + 64);
                rL1 = *(const uint4*)(Ll + k0 + 72);
                rB0 = *(const uint4*)(Rt + k0 + 64);
                rB1 = *(const uint4*)(Rt + k0 + 72);
            }
            #pragma unroll
            for (int sub = 0; sub < 2; ++sub) {
                const int kb = sub * 32 + q8;
                s16x8 ah0 = *(const s16x8*)&Ashi[(wr * 32 + l15) * LSTR + kb];
                s16x8 ah1 = *(const s16x8*)&Ashi[(wr * 32 + 16 + l15) * LSTR + kb];
                s16x8 al0 = *(const s16x8*)&Aslo[(wr * 32 + l15) * LSTR + kb];
                s16x8 al1 = *(const s16x8*)&Aslo[(wr * 32 + 16 + l15) * LSTR + kb];
                s16x8 b0  = *(const s16x8*)&Bs[(wc * 32 + l15) * LSTR + kb];
                s16x8 b1  = *(const s16x8*)&Bs[(wc * 32 + 16 + l15) * LSTR + kb];
                acc[0][0] = MFMA(ah0, b0, acc[0][0]);
                acc[0][0] = MFMA(al0, b0, acc[0][0]);
                acc[0][1] = MFMA(ah0, b1, acc[0][1]);
                acc[0][1] = MFMA(al0, b1, acc[0][1]);
                acc[1][0] = MFMA(ah1, b0, acc[1][0]);
                acc[1][0] = MFMA(al1, b0, acc[1][0]);
                acc[1][1] = MFMA(ah1, b1, acc[1][1]);
                acc[1][1] = MFMA(al1, b1, acc[1][1]);
            }
        }
    }

    const int quad = lane >> 4;
    const int m0base = rt * 64 + wr * 32;
    int colg[2];
    #pragma unroll
    for (int j = 0; j < 2; ++j) colg[j] = ct * 64 + wc * 32 + j * 16 + l15;
    float bv[2] = { u.bias[colg[0]], u.bias[colg[1]] };
    float v[2][2][4];
    #pragma unroll
    for (int i = 0; i < 2; ++i)
        #pragma unroll
        for (int j = 0; j < 2; ++j)
            #pragma unroll
            for (int r = 0; r < 4; ++r)
                v[i][j][r] = acc[i][j][r] + bv[j];

    if (u.useK6) {
        float w6[2][6];
        #pragma unroll
        for (int j = 0; j < 2; ++j)
            #pragma unroll
            for (int d = 0; d < 6; ++d)
                w6[j][d] = p.Wx0[d * 768 + u.wxColOff + colg[j]];
        #pragma unroll
        for (int i = 0; i < 2; ++i) {
            #pragma unroll
            for (int r = 0; r < 4; ++r) {
                int row = b * 256 + m0base + i * 16 + quad * 4 + r;
                const float* ax = p.Ax0 + (size_t)row * 8;
                float a0 = ax[0], a1 = ax[1], a2 = ax[2], a3 = ax[3], a4 = ax[4], a5 = ax[5];
                #pragma unroll
                for (int j = 0; j < 2; ++j)
                    v[i][j][r] += a0 * w6[j][0] + a1 * w6[j][1] + a2 * w6[j][2]
                                + a3 * w6[j][3] + a4 * w6[j][4] + a5 * w6[j][5];
            }
        }
    }

    if (p.mode == 0) {
        if (ct < 4) {
            #pragma unroll
            for (int i = 0; i < 2; ++i)
                #pragma unroll
                for (int r = 0; r < 4; ++r) {
                    int row = b * 256 + m0base + i * 16 + quad * 4 + r;
                    #pragma unroll
                    for (int j = 0; j < 2; ++j)
                        u.z[(size_t)row * 256 + colg[j]] = 1.f / (1.f + __expf(-v[i][j][r]));
                }
        } else {
            #pragma unroll
            for (int i = 0; i < 2; ++i) {
                int m0 = m0base + i * 16 + quad * 4;
                #pragma unroll
                for (int j = 0; j < 2; ++j) {
                    int colp = colg[j] - 256;
                    ushort hi4[4], lo4[4];
                    #pragma unroll
                    for (int r = 0; r < 4; ++r) {
                        int row = b * 256 + m0 + r;
                        float s = 1.f / (1.f + __expf(-v[i][j][r]));
                        float rh = s * u.h[(size_t)row * 256 + colp];
                        split2(rh, hi4[r], lo4[r]);
                    }
                    size_t off = (size_t)b * 65536 + (size_t)colp * 256 + m0;
                    *(ushort4*)&u.Thi[off] = make_ushort4(hi4[0], hi4[1], hi4[2], hi4[3]);
                    *(ushort4*)&u.Tlo[off] = make_ushort4(lo4[0], lo4[1], lo4[2], lo4[3]);
                }
            }
        }
    } else {
        #pragma unroll
        for (int i = 0; i < 2; ++i) {
            int m0 = m0base + i * 16 + quad * 4;
            #pragma unroll
            for (int j = 0; j < 2; ++j) {
                ushort hi4[4], lo4[4];
                #pragma unroll
                for (int r = 0; r < 4; ++r) {
                    int row = b * 256 + m0 + r;
                    size_t gi = (size_t)row * 256 + colg[j];
                    float c = tanhf(v[i][j][r]);
                    float zz = u.z[gi];
                    float hh = u.h[gi];
                    float hn = zz * hh + (1.f - zz) * c;
                    u.hOut[gi] = hn;
                    split2(hn, hi4[r], lo4[r]);
                }
                size_t off = (size_t)b * 65536 + (size_t)colg[j] * 256 + m0;
                *(ushort4*)&u.Thi[off] = make_ushort4(hi4[0], hi4[1], hi4[2], hi4[3]);
                *(ushort4*)&u.Tlo[off] = make_ushort4(lo4[0], lo4[1], lo4[2], lo4[3]);
            }
        }
    }
}

// ---------------------------------------------------------------------------
extern "C" void kernel_launch(void* const* d_in, const int* in_sizes, int n_in,
                              void* d_out, int out_size, void* d_ws, size_t ws_size,
                              hipStream_t stream) {
    const float* x2d  = (const float*)d_in[0];
    const float* mask = (const float*)d_in[1];
    const float* A    = (const float*)d_in[2];
    const float* Wx0  = (const float*)d_in[3];
    const float* Wh0  = (const float*)d_in[4];
    const float* b0   = (const float*)d_in[5];
    const float* Wx1  = (const float*)d_in[6];
    const float* Wh1  = (const float*)d_in[7];
    const float* b1   = (const float*)d_in[8];
    const float* Wout = (const float*)d_in[9];
    const float* bout = (const float*)d_in[10];
    float* out = (float*)d_out;

    const size_t SZ = (size_t)BN * HH;   // 524288
    float* ws = (float*)d_ws;
    float*  h0    = ws;
    float*  h1    = h0 + SZ;
    ushort* h0Thi = (ushort*)(h1 + SZ);
    ushort* h0Tlo = h0Thi + SZ;
    ushort* h1Thi = h0Tlo + SZ;
    ushort* h1Tlo = h1Thi + SZ;
    float*  z0    = (float*)(h1Tlo + SZ);
    float*  z1    = z0 + SZ;
    float*  Ax0   = z1 + SZ;             // 16384 f
    ushort* AH0hi = (ushort*)(Ax0 + 16384);   // A@h0(s-1) == Ax1 for layer1
    ushort* AH0lo = AH0hi + SZ;
    ushort* AH1hi = AH0lo + SZ;               // A@h1(s-2); reused as ARH0 after K2
    ushort* AH1lo = AH1hi + SZ;
    ushort* ARH1hi= AH1lo + SZ;
    ushort* ARH1lo= ARH1hi + SZ;
    ushort* RH0Thi= ARH1lo + SZ;
    ushort* RH0Tlo= RH0Thi + SZ;
    ushort* RH1Thi= RH0Tlo + SZ;
    ushort* RH1Tlo= RH1Thi + SZ;
    ushort* Abf   = RH1Tlo + SZ;         // 65536
    ushort* WzrT0 = Abf + 65536;         // 131072
    ushort* WcT0  = WzrT0 + 131072;      // 65536
    ushort* WxzrT1= WcT0 + 65536;        // 131072
    ushort* WhzrT1= WxzrT1 + 131072;     // 131072
    ushort* WxcT1 = WhzrT1 + 131072;     // 65536
    ushort* WhcT1 = WxcT1 + 65536;       // 65536
    // ARH0 aliases AH1: AH1 is last read in K2; ARH0 is written in K3.
    ushort* ARH0hi = AH1hi;
    ushort* ARH0lo = AH1lo;

    // zero h0,h1 (fp32) and the four transposed split buffers (bf16 zero = 0)
    hipMemsetAsync(h0, 0, (2 * SZ) * sizeof(float) + 4 * SZ * sizeof(ushort), stream);

    prep_kernel<<<dim3(2560), dim3(256), 0, stream>>>(A, Wh0, Wx1, Wh1,
        Abf, WzrT0, WcT0, WxzrT1, WhzrT1, WxcT1, WhcT1);

    // super-step s: layer0 at t=s (if s<64), layer1 at t=s-1 (if s>=1)
    for (int s = 0; s <= TT; ++s) {
        const int L0 = (s < TT);
        const int L1 = (s >= 1);

        // K1: AH0 = A@h0T, AH1 = A@h1T (+ x_job(t=s), head(t=s-2))
        { G2P p{Abf, h0Thi, h0Tlo, AH0hi, AH0lo, h1Thi, h1Tlo, AH1hi, AH1lo,
                2, L0, (s >= 2 ? s - 2 : -1), s,
                A, x2d, mask, Ax0, h1, Wout, bout, out};
          g2_kernel<<<dim3(360), dim3(256), 0, stream>>>(p); }

        // K2: zr gates — layer0 (z0, rh0T) and layer1 (z1, rh1T) combined
        { WAP2 p;
          p.u0 = WSub{AH0hi, AH0lo, WzrT0, nullptr, nullptr, nullptr, 1,
                      b0, 1, 0, h0, z0, nullptr, RH0Thi, RH0Tlo};
          p.u1 = WSub{AH0hi, AH0lo, WxzrT1, AH1hi, AH1lo, WhzrT1, 2,
                      b1, 0, 0, h1, z1, nullptr, RH1Thi, RH1Tlo};
          p.mode = 0; p.Ax0 = Ax0; p.Wx0 = Wx0;
          int g;
          if (L0 && L1) { p.nBlk0 = 256; g = 512; }
          else if (L0)  { p.nBlk0 = 256; g = 256; }
          else          { p.nBlk0 = 0;   g = 256; }
          wact_kernel<<<dim3(g), dim3(256), 0, stream>>>(p); }

        // K3: ARH0 = A@rh0T, ARH1 = A@rh1T
        { G2P p{Abf,
                L0 ? RH0Thi : RH1Thi, L0 ? RH0Tlo : RH1Tlo,
                L0 ? ARH0hi : ARH1hi, L0 ? ARH0lo : ARH1lo,
                RH1Thi, RH1Tlo, ARH1hi, ARH1lo,
                (L0 && L1) ? 2 : 1, 0, -1, s,
                A, x2d, mask, Ax0, h1, Wout, bout, out};
          g2_kernel<<<dim3(((L0 && L1) ? 2 : 1) * 128), dim3(256), 0, stream>>>(p); }

        // K4: c gate + state update — layer0 (h0, h0T) and layer1 (h1, h1T)
        { WAP2 p;
          p.u0 = WSub{ARH0hi, ARH0lo, WcT0, nullptr, nullptr, nullptr, 1,
                      b0 + 512, 1, 512, h0, z0, h0, h0Thi, h0Tlo};
          p.u1 = WSub{ARH1hi, ARH1lo, WhcT1, AH0hi, AH0lo, WxcT1, 2,
                      b1 + 512, 0, 0, h1, z1, h1, h1Thi, h1Tlo};
          p.mode = 1; p.Ax0 = Ax0; p.Wx0 = Wx0;
          int g;
          if (L0 && L1) { p.nBlk0 = 128; g = 256; }
          else if (L0)  { p.nBlk0 = 128; g = 128; }
          else          { p.nBlk0 = 0;   g = 128; }
          wact_kernel<<<dim3(g), dim3(256), 0, stream>>>(p); }
    }

    // final head for t = 63
    head_kernel<<<dim3(72), dim3(256), 0, stream>>>(h1, Wout, bout, out, TT - 1);
}